// Round 12
// baseline (360.643 us; speedup 1.0000x reference)
//
#include <hip/hip_runtime.h>
#include <math.h>

#define NN 100000
#define NE 1600000
#define D 64
#define NQ (NE / 4)

#define NBD 196                     // dst buckets, width 512 (dst>>9)
#define NBS 391                     // src buckets, width 256 (src>>8)

#define KB 500                      // partition blocks (both sides per block)
#define QPB (NQ / KB)               // 800 int4 quads per block (exact)
#define CAPD 44                     // dst cell cap, ints  (lambda 16.3, +6.9s, 1e-6 agg)
#define CAPS 36                     // src cell cap, bytes (lambda 8.2,  +9.4s, 2e-6 agg)
#define NWD (NBD * CAPD)            // 8624 staged dst words per block
#define NWS (NBS * CAPS / 4)        // 3519 staged src words per block (36 = 4*9)
#define ESCAP 8704                  // esrc LDS stage cap (bucket lambda 8192, +5.7 sigma)
#define PTB 512
#define TFB 782                     // tf1 blocks: 128 nodes each (782*128=100096)
#define AGTB 1563                   // fused agg+tf blocks: 64 nodes each (1563*64=100032)

typedef _Float16 h4v __attribute__((ext_vector_type(4)));
typedef _Float16 h8v __attribute__((ext_vector_type(8)));

// ============ tiled transform core (r7/r8-proven): 64-node tile, 4 waves ==============
__device__ __forceinline__ void tile_tf(
    const float* __restrict__ in, const float* __restrict__ W,
    const float* __restrict__ scale, _Float16* __restrict__ out,
    float* xT, int tileBase, int lt /*0..255*/)
{
    {
        int c4 = (lt & 15) << 2;
        int r0 = lt >> 4;
#pragma unroll
        for (int p = 0; p < 4; ++p) {
            int r = r0 + (p << 4);
            int node = tileBase + r;
            int nl = node < NN ? node : NN - 1;
            float4 v = *(const float4*)(in + (size_t)nl * D + c4);
            xT[(c4 + 0) * 64 + (r ^ c4)] = v.x;
            xT[(c4 + 1) * 64 + (r ^ c4)] = v.y;
            xT[(c4 + 2) * 64 + (r ^ c4)] = v.z;
            xT[(c4 + 3) * 64 + (r ^ c4)] = v.w;
        }
    }
    __syncthreads();
    int lane = lt & 63;
    int w = lt >> 6;
    int m0 = (lane >> 2) << 2;
    int nc = (w << 4) + ((lane & 3) << 2);
    float4 a0 = {0,0,0,0}, a1 = {0,0,0,0}, a2 = {0,0,0,0}, a3 = {0,0,0,0};
#pragma unroll 8
    for (int k = 0; k < 64; ++k) {
        int P = k & 60;
        float4 xa = *(const float4*)(xT + k * 64 + (m0 ^ P));
        float4 wv = *(const float4*)(W + k * D + nc);
        a0.x += xa.x * wv.x; a0.y += xa.x * wv.y; a0.z += xa.x * wv.z; a0.w += xa.x * wv.w;
        a1.x += xa.y * wv.x; a1.y += xa.y * wv.y; a1.z += xa.y * wv.z; a1.w += xa.y * wv.w;
        a2.x += xa.z * wv.x; a2.y += xa.z * wv.y; a2.z += xa.z * wv.z; a2.w += xa.z * wv.w;
        a3.x += xa.w * wv.x; a3.y += xa.w * wv.y; a3.z += xa.w * wv.z; a3.w += xa.w * wv.w;
    }
    float4 acc[4] = {a0, a1, a2, a3};
#pragma unroll
    for (int j = 0; j < 4; ++j) {
        int node = tileBase + m0 + j;
        if (node < NN) {
            float sc = scale ? scale[node] : 1.0f;
            h4v o;
            o[0] = (_Float16)(acc[j].x * sc); o[1] = (_Float16)(acc[j].y * sc);
            o[2] = (_Float16)(acc[j].z * sc); o[3] = (_Float16)(acc[j].w * sc);
            *(h4v*)(out + (size_t)node * D + nc) = o;
        }
    }
}

// ---------------- K1 (fused): blocks [0,KB) partition | [KB,KB+TFB) transform1 --------
__global__ __launch_bounds__(PTB) void partition_tf1_kernel(
    const int* __restrict__ src, const int* __restrict__ dst,
    int* __restrict__ cntD, int* __restrict__ cntS,
    int* __restrict__ pbuf, unsigned char* __restrict__ qloc,
    const float* __restrict__ x, const float* __restrict__ W1,
    _Float16* __restrict__ t_h)
{
    __shared__ __align__(16) char smem[50944];
    int t = threadIdx.x, b = blockIdx.x;
    if (b >= KB) {
        int half = t >> 8;
        int lt = t & 255;
        tile_tf(x, W1, (const float*)0, t_h,
                (float*)smem + half * (64 * 64), (b - KB) * 128 + half * 64, lt);
        return;
    }
    int* stageD = (int*)smem;                       // 8624 ints
    int* hD = (int*)(smem + 34496);                 // 196 cursors
    int* hS = (int*)(smem + 35280);                 // 391 cursors
    unsigned char* stageS = (unsigned char*)(smem + 36844);   // 14076 bytes
    for (int i = t; i < NBD; i += PTB) hD[i] = i * CAPD;
    for (int i = t; i < NBS; i += PTB) hS[i] = i * CAPS;
    __syncthreads();
    const int4* s4 = (const int4*)src + (size_t)b * QPB;
    const int4* d4 = (const int4*)dst + (size_t)b * QPB;
    for (int i = t; i < QPB; i += PTB) {
        int4 a = s4[i], d = d4[i];
        int p;
        p = atomicAdd(&hD[d.x >> 9], 1); stageD[p] = ((d.x & 511) << 17) | a.x;
        p = atomicAdd(&hD[d.y >> 9], 1); stageD[p] = ((d.y & 511) << 17) | a.y;
        p = atomicAdd(&hD[d.z >> 9], 1); stageD[p] = ((d.z & 511) << 17) | a.z;
        p = atomicAdd(&hD[d.w >> 9], 1); stageD[p] = ((d.w & 511) << 17) | a.w;
        p = atomicAdd(&hS[a.x >> 8], 1); stageS[p] = (unsigned char)(a.x & 255);
        p = atomicAdd(&hS[a.y >> 8], 1); stageS[p] = (unsigned char)(a.y & 255);
        p = atomicAdd(&hS[a.z >> 8], 1); stageS[p] = (unsigned char)(a.z & 255);
        p = atomicAdd(&hS[a.w >> 8], 1); stageS[p] = (unsigned char)(a.w & 255);
    }
    __syncthreads();
    for (int i = t; i < NWD; i += PTB) {
        int bkt = i / CAPD, slot = i - bkt * CAPD;
        pbuf[((size_t)bkt * KB + b) * CAPD + slot] = stageD[i];
    }
    const int* stageS_w = (const int*)(smem + 36844);
    int* qloc_w = (int*)qloc;
    for (int i = t; i < NWS; i += PTB) {
        int bkt = i / 9, sw = i - bkt * 9;
        qloc_w[((size_t)bkt * KB + b) * 9 + sw] = stageS_w[i];
    }
    for (int i = t; i < NBD; i += PTB) cntD[i * KB + b] = hD[i] - i * CAPD;
    for (int i = t; i < NBS; i += PTB) cntS[i * KB + b] = hS[i] - i * CAPS;
}

// ---------------- K2: per-bucket totals ----------------
__global__ __launch_bounds__(256) void scan1_kernel(const int* __restrict__ cntD,
                                                    int* __restrict__ btot) {
    int B = blockIdx.x, t = threadIdx.x;
    __shared__ int ps[4];
    int s = 0;
    for (int j = t; j < KB; j += 256) s += cntD[B * KB + j];
    for (int o = 32; o > 0; o >>= 1) s += __shfl_xor(s, o, 64);
    if ((t & 63) == 0) ps[t >> 6] = s;
    __syncthreads();
    if (t == 0) btot[B] = ps[0] + ps[1] + ps[2] + ps[3];
}

// ---------------- K3: finalize — in-block prefix, LDS-staged esrc (r10-proven) --------
__global__ __launch_bounds__(PTB) void finalize_kernel(
    const int* __restrict__ pbuf, const unsigned char* __restrict__ qloc,
    const int* __restrict__ cntD, const int* __restrict__ cntS,
    const int* __restrict__ btot,
    int* __restrict__ row_ptr, float* __restrict__ nsrc,
    float* __restrict__ ndst, int* __restrict__ esrc)
{
    int B = blockIdx.x, t = threadIdx.x;
    int lane = t & 63, w = t >> 6;
    if (B >= NBD) {
        int q = B - NBD;
        __shared__ int h[256];
        __shared__ int cs[KB];
        if (t < 256) h[t] = 0;
        if (t < KB) cs[t] = cntS[q * KB + t];
        __syncthreads();
        for (int r0 = 0; r0 < KB; r0 += 64) {
            int r = r0 + (w << 3) + (lane >> 3);
            if (r < KB) {
                int c = cs[r];
                const unsigned char* run = qloc + ((size_t)q * KB + r) * CAPS;
                for (int k = lane & 7; k < c; k += 8) atomicAdd(&h[run[k]], 1);
            }
        }
        __syncthreads();
        if (t < 256) {
            int n = (q << 8) + t;
            if (n < NN) nsrc[n] = 1.0f / sqrtf(fmaxf((float)h[t], 1.0f));
        }
        return;
    }
    __shared__ int fh[512], fcur[512];
    __shared__ int cl[KB];
    __shared__ int stage[ESCAP];
    __shared__ int sbeg;
    if (t < KB) cl[t] = cntD[B * KB + t];
    for (int i = t; i < 512; i += PTB) fh[i] = 0;
    if (w == 0) {
        int s = 0;
        for (int j = lane; j < B; j += 64) s += btot[j];
        for (int o = 32; o > 0; o >>= 1) s += __shfl_xor(s, o, 64);
        if (lane == 0) sbeg = s;
    }
    if (B == 0 && t == 128) row_ptr[NN] = NE;
    __syncthreads();
    int beg = sbeg;
    for (int r0 = 0; r0 < KB; r0 += 32) {
        int r = r0 + (w << 2) + (lane >> 4);
        if (r < KB) {
            int c = cl[r];
            const int* run = pbuf + ((size_t)B * KB + r) * CAPD;
            for (int k = lane & 15; k < c; k += 16) atomicAdd(&fh[run[k] >> 17], 1);
        }
    }
    __syncthreads();
    if (w == 0) {
        int v[8];
        int s = 0;
#pragma unroll
        for (int j = 0; j < 8; ++j) { v[j] = fh[lane * 8 + j]; s += v[j]; }
        int incl = s;
        for (int o = 1; o < 64; o <<= 1) {
            int u = __shfl_up(incl, o, 64);
            if (lane >= o) incl += u;
        }
        int run = incl - s;
#pragma unroll
        for (int j = 0; j < 8; ++j) {
            int bin = lane * 8 + j;
            fcur[bin] = run;
            int n = (B << 9) + bin;
            if (n < NN) {
                row_ptr[n] = beg + run;
                ndst[n] = 1.0f / sqrtf(fmaxf((float)v[j], 1.0f));
            }
            run += v[j];
        }
    }
    __syncthreads();
    for (int r0 = 0; r0 < KB; r0 += 32) {
        int r = r0 + (w << 2) + (lane >> 4);
        if (r < KB) {
            int c = cl[r];
            const int* run = pbuf + ((size_t)B * KB + r) * CAPD;
            for (int k = lane & 15; k < c; k += 16) {
                int v = run[k];
                int p = atomicAdd(&fcur[v >> 17], 1);
                stage[p] = v & 0x1FFFF;
            }
        }
    }
    __syncthreads();
    int cnt = btot[B];
    for (int i = t; i < cnt; i += PTB) esrc[beg + i] = stage[i];
}

// ---------------- K4 (fused): aggregate-1 + transform-2 (r11-proven) ----------------
__global__ __launch_bounds__(256) void agg_tf_kernel(
    const _Float16* __restrict__ t, const int* __restrict__ row_ptr,
    const int* __restrict__ esrc, const float* __restrict__ nsrc,
    const float* __restrict__ ndst, const float* __restrict__ bias,
    const float* __restrict__ W, _Float16* __restrict__ out)
{
    __shared__ float xT[64 * 64];       // 16 KB
    int tid = threadIdx.x;
    int lane = tid & 63, wv = tid >> 6;     // 4 waves
    int tileBase = blockIdx.x * 64;
    int quad = lane >> 4;
    int l4 = lane & 15;
    int g = l4 >> 3, c = l4 & 7;
    float4 blo = *(const float4*)(bias + (c << 3));
    float4 bhi = *(const float4*)(bias + (c << 3) + 4);
#pragma unroll 1
    for (int pass = 0; pass < 4; ++pass) {
        int m = (wv << 4) + (pass << 2) + quad;     // node-in-tile 0..63
        int node = tileBase + m;
        float a0[8] = {0,0,0,0,0,0,0,0};
        float a1[8] = {0,0,0,0,0,0,0,0};
        float h[8];
        if (node < NN) {
            int beg = row_ptr[node], end = row_ptr[node + 1];
            int i = beg;
            for (; i + 4 <= end; i += 4) {
                int s0 = esrc[i + g];
                int s1 = esrc[i + 2 + g];
                float ns0 = nsrc[s0];
                float ns1 = nsrc[s1];
                h8v v0 = *(const h8v*)(t + (size_t)s0 * D + (c << 3));
                h8v v1 = *(const h8v*)(t + (size_t)s1 * D + (c << 3));
#pragma unroll
                for (int j = 0; j < 8; ++j) {
                    a0[j] += (float)v0[j] * ns0;
                    a1[j] += (float)v1[j] * ns1;
                }
            }
            for (; i < end; i += 2) {
                int e = i + g;
                if (e < end) {
                    int s = esrc[e];
                    float ns = nsrc[s];
                    h8v v = *(const h8v*)(t + (size_t)s * D + (c << 3));
#pragma unroll
                    for (int j = 0; j < 8; ++j) a0[j] += (float)v[j] * ns;
                }
            }
#pragma unroll
            for (int j = 0; j < 8; ++j) a0[j] += a1[j];
#pragma unroll
            for (int j = 0; j < 8; ++j) a0[j] += __shfl_xor(a0[j], 8, 64);
            float nd = ndst[node];
            h[0] = fmaxf(a0[0] * nd + blo.x, 0.f); h[1] = fmaxf(a0[1] * nd + blo.y, 0.f);
            h[2] = fmaxf(a0[2] * nd + blo.z, 0.f); h[3] = fmaxf(a0[3] * nd + blo.w, 0.f);
            h[4] = fmaxf(a0[4] * nd + bhi.x, 0.f); h[5] = fmaxf(a0[5] * nd + bhi.y, 0.f);
            h[6] = fmaxf(a0[6] * nd + bhi.z, 0.f); h[7] = fmaxf(a0[7] * nd + bhi.w, 0.f);
        } else {
#pragma unroll
            for (int j = 0; j < 8; ++j) h[j] = 0.f;
        }
#pragma unroll
        for (int j = 0; j < 4; ++j) {
            int k = (c << 3) + (g << 2) + j;
            xT[k * 64 + (m ^ (k & 60))] = h[(g << 2) + j];
        }
    }
    __syncthreads();
    int m0 = (lane >> 2) << 2;
    int nc = (wv << 4) + ((lane & 3) << 2);
    float4 b0 = {0,0,0,0}, b1_ = {0,0,0,0}, b2_ = {0,0,0,0}, b3 = {0,0,0,0};
#pragma unroll 8
    for (int k = 0; k < 64; ++k) {
        int P = k & 60;
        float4 xa = *(const float4*)(xT + k * 64 + (m0 ^ P));
        float4 wv4 = *(const float4*)(W + k * D + nc);
        b0.x += xa.x * wv4.x; b0.y += xa.x * wv4.y; b0.z += xa.x * wv4.z; b0.w += xa.x * wv4.w;
        b1_.x += xa.y * wv4.x; b1_.y += xa.y * wv4.y; b1_.z += xa.y * wv4.z; b1_.w += xa.y * wv4.w;
        b2_.x += xa.z * wv4.x; b2_.y += xa.z * wv4.y; b2_.z += xa.z * wv4.z; b2_.w += xa.z * wv4.w;
        b3.x += xa.w * wv4.x; b3.y += xa.w * wv4.y; b3.z += xa.w * wv4.z; b3.w += xa.w * wv4.w;
    }
    float4 acc[4] = {b0, b1_, b2_, b3};
#pragma unroll
    for (int j = 0; j < 4; ++j) {
        int node = tileBase + m0 + j;
        if (node < NN) {
            float sc = nsrc[node];
            h4v o;
            o[0] = (_Float16)(acc[j].x * sc); o[1] = (_Float16)(acc[j].y * sc);
            o[2] = (_Float16)(acc[j].z * sc); o[3] = (_Float16)(acc[j].w * sc);
            *(h4v*)(out + (size_t)node * D + nc) = o;
        }
    }
}

// ---------------- K5: aggregation layer 2 — XCD channel-panel split ----------------
// panel = bid & 7 pins all blocks of one 16B channel-slice onto one XCD (round-robin
// blockIdx->XCD; perf heuristic only, correctness independent). Each XCD's working set
// of t2 = 100K x 16B = 1.6MB < 4MB L2 -> gathers become L2 hits (vs 12.8MB thrash to
// L3 at ~600cy that saturated chain-scaling in r10). Per 16-lane group: one node, each
// lane gathers a DIFFERENT edge's 16B slice -> 64 edges per wave per vmcnt wait.
// esrc is read 8x (51MB) as nontemporal to protect panel residency.
__global__ __launch_bounds__(256) void agg2_panel_kernel(
    const _Float16* __restrict__ t, const int* __restrict__ row_ptr,
    const int* __restrict__ esrc, const float* __restrict__ ndst,
    const float* __restrict__ bias, float* __restrict__ out)
{
    int bid = blockIdx.x;
    int panel = bid & 7;
    int nb = bid >> 3;
    int tid = threadIdx.x;
    int lane = tid & 63, wv = tid >> 6;
    int grp = lane >> 4;                // node-group within wave
    int l4 = lane & 15;                 // edge slot
    int node = nb * 16 + (wv << 2) + grp;
    if (node >= NN) return;
    int beg = row_ptr[node], end = row_ptr[node + 1];
    const _Float16* tp = t + (panel << 3);
    float a[8] = {0,0,0,0,0,0,0,0};
    for (int i = beg + l4; i < end; i += 16) {
        int s = __builtin_nontemporal_load(&esrc[i]);
        h8v v = *(const h8v*)(tp + (size_t)s * D);
#pragma unroll
        for (int j = 0; j < 8; ++j) a[j] += (float)v[j];
    }
    // reduce across the 16 edge-slot lanes
#pragma unroll
    for (int j = 0; j < 8; ++j) {
        a[j] += __shfl_xor(a[j], 1, 64);
        a[j] += __shfl_xor(a[j], 2, 64);
        a[j] += __shfl_xor(a[j], 4, 64);
        a[j] += __shfl_xor(a[j], 8, 64);
    }
    if (l4 == 0) {
        float nd = ndst[node];
        float4 blo = *(const float4*)(bias + (panel << 3));
        float4 bhi = *(const float4*)(bias + (panel << 3) + 4);
        float4 o0 = {a[0] * nd + blo.x, a[1] * nd + blo.y,
                     a[2] * nd + blo.z, a[3] * nd + blo.w};
        float4 o1 = {a[4] * nd + bhi.x, a[5] * nd + bhi.y,
                     a[6] * nd + bhi.z, a[7] * nd + bhi.w};
        *(float4*)(out + (size_t)node * D + (panel << 3)) = o0;
        *(float4*)(out + (size_t)node * D + (panel << 3) + 4) = o1;
    }
}

// ---------------- launcher ----------------
extern "C" void kernel_launch(void* const* d_in, const int* in_sizes, int n_in,
                              void* d_out, int out_size, void* d_ws, size_t ws_size,
                              hipStream_t stream) {
    const float* x  = (const float*)d_in[0];
    const int* src  = (const int*)d_in[1];
    const int* dst  = (const int*)d_in[2];
    const float* W1 = (const float*)d_in[3];
    const float* b1 = (const float*)d_in[4];
    const float* W2 = (const float*)d_in[5];
    const float* b2 = (const float*)d_in[6];
    float* out = (float*)d_out;

    size_t off = 0;
    auto alloc = [&](size_t bytes) -> void* {
        void* p = (char*)d_ws + off;
        off += (bytes + 255) & ~(size_t)255;
        return p;
    };
    int* row_ptr  = (int*)alloc((size_t)(NN + 1) * 4);
    float* nsrc   = (float*)alloc((size_t)NN * 4);
    float* ndst   = (float*)alloc((size_t)NN * 4);
    int* btot     = (int*)alloc((size_t)256 * 4);
    int* cntD     = (int*)alloc((size_t)NBD * KB * 4);           // 392 KB
    int* cntS     = (int*)alloc((size_t)NBS * KB * 4);           // 782 KB
    int* esrc     = (int*)alloc((size_t)NE * 4);                 // 6.4 MB
    _Float16* t_h = (_Float16*)alloc((size_t)NN * D * 2);        // 12.8 MB
    // scratch region: pbuf 17.2MB + qloc 7.0MB = 24.2MB; dead after finalize,
    // then t2 (12.8MB fp16) aliases its start.
    char* scratch = (char*)alloc((size_t)NBD * KB * CAPD * 4 + (size_t)NBS * KB * CAPS);
    (void)ws_size;
    int* pbuf = (int*)scratch;
    unsigned char* qloc = (unsigned char*)(pbuf + (size_t)NBD * KB * CAPD);
    _Float16* t2 = (_Float16*)scratch;

    partition_tf1_kernel<<<KB + TFB, PTB, 0, stream>>>(src, dst, cntD, cntS,
                                                       pbuf, qloc, x, W1, t_h);
    scan1_kernel<<<NBD, 256, 0, stream>>>(cntD, btot);
    finalize_kernel<<<NBD + NBS, PTB, 0, stream>>>(pbuf, qloc, cntD, cntS, btot,
                                                   row_ptr, nsrc, ndst, esrc);

    agg_tf_kernel<<<AGTB, 256, 0, stream>>>(t_h, row_ptr, esrc, nsrc, ndst, b1, W2, t2);
    // 8 panels x 6250 node-blocks (16 nodes/block); panel = bid&7 -> per-XCD L2 pinning
    agg2_panel_kernel<<<8 * 6250, 256, 0, stream>>>(t2, row_ptr, esrc, ndst, b2, out);
}

// Round 13
// 262.934 us; speedup vs baseline: 1.3716x; 1.3716x over previous
//
#include <hip/hip_runtime.h>
#include <math.h>

#define NN 100000
#define NE 1600000
#define D 64
#define NQ (NE / 4)

#define NBD 196                     // dst buckets, width 512 (dst>>9)
#define NBS 391                     // src buckets, width 256 (src>>8)

#define KB 500                      // partition blocks (both sides per block)
#define QPB (NQ / KB)               // 800 int4 quads per block (exact)
#define CAPD 44                     // dst cell cap, ints  (lambda 16.3, +6.9s, 1e-6 agg)
#define CAPS 36                     // src cell cap, bytes (lambda 8.2,  +9.4s, 2e-6 agg)
#define NWD (NBD * CAPD)            // 8624 staged dst words per block
#define NWS (NBS * CAPS / 4)        // 3519 staged src words per block (36 = 4*9)
#define ESCAP 8704                  // esrc LDS stage cap (bucket lambda 8192, +5.7 sigma)
#define PTB 512
#define TFB 782                     // tf1 blocks: 128 nodes each (782*128=100096)
#define AGTB 1563                   // fused agg+tf blocks: 64 nodes each (1563*64=100032)

typedef _Float16 h4v __attribute__((ext_vector_type(4)));
typedef _Float16 h8v __attribute__((ext_vector_type(8)));

// ============ tiled transform core (r7/r8-proven): 64-node tile, 4 waves ==============
__device__ __forceinline__ void tile_tf(
    const float* __restrict__ in, const float* __restrict__ W,
    const float* __restrict__ scale, _Float16* __restrict__ out,
    float* xT, int tileBase, int lt /*0..255*/)
{
    {
        int c4 = (lt & 15) << 2;
        int r0 = lt >> 4;
#pragma unroll
        for (int p = 0; p < 4; ++p) {
            int r = r0 + (p << 4);
            int node = tileBase + r;
            int nl = node < NN ? node : NN - 1;
            float4 v = *(const float4*)(in + (size_t)nl * D + c4);
            xT[(c4 + 0) * 64 + (r ^ c4)] = v.x;
            xT[(c4 + 1) * 64 + (r ^ c4)] = v.y;
            xT[(c4 + 2) * 64 + (r ^ c4)] = v.z;
            xT[(c4 + 3) * 64 + (r ^ c4)] = v.w;
        }
    }
    __syncthreads();
    int lane = lt & 63;
    int w = lt >> 6;
    int m0 = (lane >> 2) << 2;
    int nc = (w << 4) + ((lane & 3) << 2);
    float4 a0 = {0,0,0,0}, a1 = {0,0,0,0}, a2 = {0,0,0,0}, a3 = {0,0,0,0};
#pragma unroll 8
    for (int k = 0; k < 64; ++k) {
        int P = k & 60;
        float4 xa = *(const float4*)(xT + k * 64 + (m0 ^ P));
        float4 wv = *(const float4*)(W + k * D + nc);
        a0.x += xa.x * wv.x; a0.y += xa.x * wv.y; a0.z += xa.x * wv.z; a0.w += xa.x * wv.w;
        a1.x += xa.y * wv.x; a1.y += xa.y * wv.y; a1.z += xa.y * wv.z; a1.w += xa.y * wv.w;
        a2.x += xa.z * wv.x; a2.y += xa.z * wv.y; a2.z += xa.z * wv.z; a2.w += xa.z * wv.w;
        a3.x += xa.w * wv.x; a3.y += xa.w * wv.y; a3.z += xa.w * wv.z; a3.w += xa.w * wv.w;
    }
    float4 acc[4] = {a0, a1, a2, a3};
#pragma unroll
    for (int j = 0; j < 4; ++j) {
        int node = tileBase + m0 + j;
        if (node < NN) {
            float sc = scale ? scale[node] : 1.0f;
            h4v o;
            o[0] = (_Float16)(acc[j].x * sc); o[1] = (_Float16)(acc[j].y * sc);
            o[2] = (_Float16)(acc[j].z * sc); o[3] = (_Float16)(acc[j].w * sc);
            *(h4v*)(out + (size_t)node * D + nc) = o;
        }
    }
}

// ---------------- K1 (fused): blocks [0,KB) partition | [KB,KB+TFB) transform1 --------
__global__ __launch_bounds__(PTB) void partition_tf1_kernel(
    const int* __restrict__ src, const int* __restrict__ dst,
    int* __restrict__ cntD, int* __restrict__ cntS,
    int* __restrict__ pbuf, unsigned char* __restrict__ qloc,
    const float* __restrict__ x, const float* __restrict__ W1,
    _Float16* __restrict__ t_h)
{
    __shared__ __align__(16) char smem[50944];
    int t = threadIdx.x, b = blockIdx.x;
    if (b >= KB) {
        int half = t >> 8;
        int lt = t & 255;
        tile_tf(x, W1, (const float*)0, t_h,
                (float*)smem + half * (64 * 64), (b - KB) * 128 + half * 64, lt);
        return;
    }
    int* stageD = (int*)smem;                       // 8624 ints
    int* hD = (int*)(smem + 34496);                 // 196 cursors
    int* hS = (int*)(smem + 35280);                 // 391 cursors
    unsigned char* stageS = (unsigned char*)(smem + 36844);   // 14076 bytes
    for (int i = t; i < NBD; i += PTB) hD[i] = i * CAPD;
    for (int i = t; i < NBS; i += PTB) hS[i] = i * CAPS;
    __syncthreads();
    const int4* s4 = (const int4*)src + (size_t)b * QPB;
    const int4* d4 = (const int4*)dst + (size_t)b * QPB;
    for (int i = t; i < QPB; i += PTB) {
        int4 a = s4[i], d = d4[i];
        int p;
        p = atomicAdd(&hD[d.x >> 9], 1); stageD[p] = ((d.x & 511) << 17) | a.x;
        p = atomicAdd(&hD[d.y >> 9], 1); stageD[p] = ((d.y & 511) << 17) | a.y;
        p = atomicAdd(&hD[d.z >> 9], 1); stageD[p] = ((d.z & 511) << 17) | a.z;
        p = atomicAdd(&hD[d.w >> 9], 1); stageD[p] = ((d.w & 511) << 17) | a.w;
        p = atomicAdd(&hS[a.x >> 8], 1); stageS[p] = (unsigned char)(a.x & 255);
        p = atomicAdd(&hS[a.y >> 8], 1); stageS[p] = (unsigned char)(a.y & 255);
        p = atomicAdd(&hS[a.z >> 8], 1); stageS[p] = (unsigned char)(a.z & 255);
        p = atomicAdd(&hS[a.w >> 8], 1); stageS[p] = (unsigned char)(a.w & 255);
    }
    __syncthreads();
    for (int i = t; i < NWD; i += PTB) {
        int bkt = i / CAPD, slot = i - bkt * CAPD;
        pbuf[((size_t)bkt * KB + b) * CAPD + slot] = stageD[i];
    }
    const int* stageS_w = (const int*)(smem + 36844);
    int* qloc_w = (int*)qloc;
    for (int i = t; i < NWS; i += PTB) {
        int bkt = i / 9, sw = i - bkt * 9;
        qloc_w[((size_t)bkt * KB + b) * 9 + sw] = stageS_w[i];
    }
    for (int i = t; i < NBD; i += PTB) cntD[i * KB + b] = hD[i] - i * CAPD;
    for (int i = t; i < NBS; i += PTB) cntS[i * KB + b] = hS[i] - i * CAPS;
}

// ---------------- K2: per-bucket totals ----------------
__global__ __launch_bounds__(256) void scan1_kernel(const int* __restrict__ cntD,
                                                    int* __restrict__ btot) {
    int B = blockIdx.x, t = threadIdx.x;
    __shared__ int ps[4];
    int s = 0;
    for (int j = t; j < KB; j += 256) s += cntD[B * KB + j];
    for (int o = 32; o > 0; o >>= 1) s += __shfl_xor(s, o, 64);
    if ((t & 63) == 0) ps[t >> 6] = s;
    __syncthreads();
    if (t == 0) btot[B] = ps[0] + ps[1] + ps[2] + ps[3];
}

// ---------------- K3: finalize — in-block prefix, LDS-staged esrc (r10-proven) --------
__global__ __launch_bounds__(PTB) void finalize_kernel(
    const int* __restrict__ pbuf, const unsigned char* __restrict__ qloc,
    const int* __restrict__ cntD, const int* __restrict__ cntS,
    const int* __restrict__ btot,
    int* __restrict__ row_ptr, float* __restrict__ nsrc,
    float* __restrict__ ndst, int* __restrict__ esrc)
{
    int B = blockIdx.x, t = threadIdx.x;
    int lane = t & 63, w = t >> 6;
    if (B >= NBD) {
        int q = B - NBD;
        __shared__ int h[256];
        __shared__ int cs[KB];
        if (t < 256) h[t] = 0;
        if (t < KB) cs[t] = cntS[q * KB + t];
        __syncthreads();
        for (int r0 = 0; r0 < KB; r0 += 64) {
            int r = r0 + (w << 3) + (lane >> 3);
            if (r < KB) {
                int c = cs[r];
                const unsigned char* run = qloc + ((size_t)q * KB + r) * CAPS;
                for (int k = lane & 7; k < c; k += 8) atomicAdd(&h[run[k]], 1);
            }
        }
        __syncthreads();
        if (t < 256) {
            int n = (q << 8) + t;
            if (n < NN) nsrc[n] = 1.0f / sqrtf(fmaxf((float)h[t], 1.0f));
        }
        return;
    }
    __shared__ int fh[512], fcur[512];
    __shared__ int cl[KB];
    __shared__ int stage[ESCAP];
    __shared__ int sbeg;
    if (t < KB) cl[t] = cntD[B * KB + t];
    for (int i = t; i < 512; i += PTB) fh[i] = 0;
    if (w == 0) {
        int s = 0;
        for (int j = lane; j < B; j += 64) s += btot[j];
        for (int o = 32; o > 0; o >>= 1) s += __shfl_xor(s, o, 64);
        if (lane == 0) sbeg = s;
    }
    if (B == 0 && t == 128) row_ptr[NN] = NE;
    __syncthreads();
    int beg = sbeg;
    for (int r0 = 0; r0 < KB; r0 += 32) {
        int r = r0 + (w << 2) + (lane >> 4);
        if (r < KB) {
            int c = cl[r];
            const int* run = pbuf + ((size_t)B * KB + r) * CAPD;
            for (int k = lane & 15; k < c; k += 16) atomicAdd(&fh[run[k] >> 17], 1);
        }
    }
    __syncthreads();
    if (w == 0) {
        int v[8];
        int s = 0;
#pragma unroll
        for (int j = 0; j < 8; ++j) { v[j] = fh[lane * 8 + j]; s += v[j]; }
        int incl = s;
        for (int o = 1; o < 64; o <<= 1) {
            int u = __shfl_up(incl, o, 64);
            if (lane >= o) incl += u;
        }
        int run = incl - s;
#pragma unroll
        for (int j = 0; j < 8; ++j) {
            int bin = lane * 8 + j;
            fcur[bin] = run;
            int n = (B << 9) + bin;
            if (n < NN) {
                row_ptr[n] = beg + run;
                ndst[n] = 1.0f / sqrtf(fmaxf((float)v[j], 1.0f));
            }
            run += v[j];
        }
    }
    __syncthreads();
    for (int r0 = 0; r0 < KB; r0 += 32) {
        int r = r0 + (w << 2) + (lane >> 4);
        if (r < KB) {
            int c = cl[r];
            const int* run = pbuf + ((size_t)B * KB + r) * CAPD;
            for (int k = lane & 15; k < c; k += 16) {
                int v = run[k];
                int p = atomicAdd(&fcur[v >> 17], 1);
                stage[p] = v & 0x1FFFF;
            }
        }
    }
    __syncthreads();
    int cnt = btot[B];
    for (int i = t; i < cnt; i += PTB) esrc[beg + i] = stage[i];
}

// ---------------- K4 (fused): aggregate-1 + transform-2, PANEL-MAJOR t2 output --------
// r11-proven structure; only phase-B's output layout changes: t2p[panel][node][8]
// (panel = channel>>3). r12 lesson: row-major t2 shares cache lines across panels,
// voiding per-XCD residency and causing 8x HBM over-fetch (610MB).
__global__ __launch_bounds__(256) void agg_tf_kernel(
    const _Float16* __restrict__ t, const int* __restrict__ row_ptr,
    const int* __restrict__ esrc, const float* __restrict__ nsrc,
    const float* __restrict__ ndst, const float* __restrict__ bias,
    const float* __restrict__ W, _Float16* __restrict__ out)
{
    __shared__ float xT[64 * 64];       // 16 KB
    int tid = threadIdx.x;
    int lane = tid & 63, wv = tid >> 6;     // 4 waves
    int tileBase = blockIdx.x * 64;
    int quad = lane >> 4;
    int l4 = lane & 15;
    int g = l4 >> 3, c = l4 & 7;
    float4 blo = *(const float4*)(bias + (c << 3));
    float4 bhi = *(const float4*)(bias + (c << 3) + 4);
#pragma unroll 1
    for (int pass = 0; pass < 4; ++pass) {
        int m = (wv << 4) + (pass << 2) + quad;     // node-in-tile 0..63
        int node = tileBase + m;
        float a0[8] = {0,0,0,0,0,0,0,0};
        float a1[8] = {0,0,0,0,0,0,0,0};
        float h[8];
        if (node < NN) {
            int beg = row_ptr[node], end = row_ptr[node + 1];
            int i = beg;
            for (; i + 4 <= end; i += 4) {
                int s0 = esrc[i + g];
                int s1 = esrc[i + 2 + g];
                float ns0 = nsrc[s0];
                float ns1 = nsrc[s1];
                h8v v0 = *(const h8v*)(t + (size_t)s0 * D + (c << 3));
                h8v v1 = *(const h8v*)(t + (size_t)s1 * D + (c << 3));
#pragma unroll
                for (int j = 0; j < 8; ++j) {
                    a0[j] += (float)v0[j] * ns0;
                    a1[j] += (float)v1[j] * ns1;
                }
            }
            for (; i < end; i += 2) {
                int e = i + g;
                if (e < end) {
                    int s = esrc[e];
                    float ns = nsrc[s];
                    h8v v = *(const h8v*)(t + (size_t)s * D + (c << 3));
#pragma unroll
                    for (int j = 0; j < 8; ++j) a0[j] += (float)v[j] * ns;
                }
            }
#pragma unroll
            for (int j = 0; j < 8; ++j) a0[j] += a1[j];
#pragma unroll
            for (int j = 0; j < 8; ++j) a0[j] += __shfl_xor(a0[j], 8, 64);
            float nd = ndst[node];
            h[0] = fmaxf(a0[0] * nd + blo.x, 0.f); h[1] = fmaxf(a0[1] * nd + blo.y, 0.f);
            h[2] = fmaxf(a0[2] * nd + blo.z, 0.f); h[3] = fmaxf(a0[3] * nd + blo.w, 0.f);
            h[4] = fmaxf(a0[4] * nd + bhi.x, 0.f); h[5] = fmaxf(a0[5] * nd + bhi.y, 0.f);
            h[6] = fmaxf(a0[6] * nd + bhi.z, 0.f); h[7] = fmaxf(a0[7] * nd + bhi.w, 0.f);
        } else {
#pragma unroll
            for (int j = 0; j < 8; ++j) h[j] = 0.f;
        }
#pragma unroll
        for (int j = 0; j < 4; ++j) {
            int k = (c << 3) + (g << 2) + j;
            xT[k * 64 + (m ^ (k & 60))] = h[(g << 2) + j];
        }
    }
    __syncthreads();
    int m0 = (lane >> 2) << 2;
    int nc = (wv << 4) + ((lane & 3) << 2);
    float4 b0 = {0,0,0,0}, b1_ = {0,0,0,0}, b2_ = {0,0,0,0}, b3 = {0,0,0,0};
#pragma unroll 8
    for (int k = 0; k < 64; ++k) {
        int P = k & 60;
        float4 xa = *(const float4*)(xT + k * 64 + (m0 ^ P));
        float4 wv4 = *(const float4*)(W + k * D + nc);
        b0.x += xa.x * wv4.x; b0.y += xa.x * wv4.y; b0.z += xa.x * wv4.z; b0.w += xa.x * wv4.w;
        b1_.x += xa.y * wv4.x; b1_.y += xa.y * wv4.y; b1_.z += xa.y * wv4.z; b1_.w += xa.y * wv4.w;
        b2_.x += xa.z * wv4.x; b2_.y += xa.z * wv4.y; b2_.z += xa.z * wv4.z; b2_.w += xa.z * wv4.w;
        b3.x += xa.w * wv4.x; b3.y += xa.w * wv4.y; b3.z += xa.w * wv4.z; b3.w += xa.w * wv4.w;
    }
    float4 acc[4] = {b0, b1_, b2_, b3};
    int pnl = nc >> 3;                  // panel of this 4-channel chunk
    int po = nc & 7;                    // offset within panel (0 or 4)
    _Float16* outp = out + (size_t)pnl * NN * 8 + po;
#pragma unroll
    for (int j = 0; j < 4; ++j) {
        int node = tileBase + m0 + j;
        if (node < NN) {
            float sc = nsrc[node];
            h4v o;
            o[0] = (_Float16)(acc[j].x * sc); o[1] = (_Float16)(acc[j].y * sc);
            o[2] = (_Float16)(acc[j].z * sc); o[3] = (_Float16)(acc[j].w * sc);
            *(h4v*)(outp + (size_t)node * 8) = o;
        }
    }
}

// ---------------- K5: aggregation layer 2 — panel-major XCD split ----------------
// panel = bid & 7 (round-robin block->XCD default). Panel region = contiguous 1.6MB
// (< 4MB per-XCD L2) -> gathers are L2 hits; no cross-panel line sharing (r12 fix).
// 16 lanes per node, each lane gathers a DIFFERENT edge's 16B -> 64 edges/wave in
// flight. esrc read with plain loads (L3-cached across panels).
__global__ __launch_bounds__(256) void agg2_panel_kernel(
    const _Float16* __restrict__ t2p, const int* __restrict__ row_ptr,
    const int* __restrict__ esrc, const float* __restrict__ ndst,
    const float* __restrict__ bias, float* __restrict__ out)
{
    int bid = blockIdx.x;
    int panel = bid & 7;
    int nb = bid >> 3;
    int tid = threadIdx.x;
    int lane = tid & 63, wv = tid >> 6;
    int grp = lane >> 4;                // node-group within wave
    int l4 = lane & 15;                 // edge slot
    int node = nb * 16 + (wv << 2) + grp;
    if (node >= NN) return;
    int beg = row_ptr[node], end = row_ptr[node + 1];
    const _Float16* tp = t2p + (size_t)panel * NN * 8;
    float a[8] = {0,0,0,0,0,0,0,0};
    for (int i = beg + l4; i < end; i += 16) {
        int s = esrc[i];
        h8v v = *(const h8v*)(tp + (size_t)s * 8);
#pragma unroll
        for (int j = 0; j < 8; ++j) a[j] += (float)v[j];
    }
#pragma unroll
    for (int j = 0; j < 8; ++j) {
        a[j] += __shfl_xor(a[j], 1, 64);
        a[j] += __shfl_xor(a[j], 2, 64);
        a[j] += __shfl_xor(a[j], 4, 64);
        a[j] += __shfl_xor(a[j], 8, 64);
    }
    if (l4 == 0) {
        float nd = ndst[node];
        float4 blo = *(const float4*)(bias + (panel << 3));
        float4 bhi = *(const float4*)(bias + (panel << 3) + 4);
        float4 o0 = {a[0] * nd + blo.x, a[1] * nd + blo.y,
                     a[2] * nd + blo.z, a[3] * nd + blo.w};
        float4 o1 = {a[4] * nd + bhi.x, a[5] * nd + bhi.y,
                     a[6] * nd + bhi.z, a[7] * nd + bhi.w};
        *(float4*)(out + (size_t)node * D + (panel << 3)) = o0;
        *(float4*)(out + (size_t)node * D + (panel << 3) + 4) = o1;
    }
}

// ---------------- launcher ----------------
extern "C" void kernel_launch(void* const* d_in, const int* in_sizes, int n_in,
                              void* d_out, int out_size, void* d_ws, size_t ws_size,
                              hipStream_t stream) {
    const float* x  = (const float*)d_in[0];
    const int* src  = (const int*)d_in[1];
    const int* dst  = (const int*)d_in[2];
    const float* W1 = (const float*)d_in[3];
    const float* b1 = (const float*)d_in[4];
    const float* W2 = (const float*)d_in[5];
    const float* b2 = (const float*)d_in[6];
    float* out = (float*)d_out;

    size_t off = 0;
    auto alloc = [&](size_t bytes) -> void* {
        void* p = (char*)d_ws + off;
        off += (bytes + 255) & ~(size_t)255;
        return p;
    };
    int* row_ptr  = (int*)alloc((size_t)(NN + 1) * 4);
    float* nsrc   = (float*)alloc((size_t)NN * 4);
    float* ndst   = (float*)alloc((size_t)NN * 4);
    int* btot     = (int*)alloc((size_t)256 * 4);
    int* cntD     = (int*)alloc((size_t)NBD * KB * 4);           // 392 KB
    int* cntS     = (int*)alloc((size_t)NBS * KB * 4);           // 782 KB
    int* esrc     = (int*)alloc((size_t)NE * 4);                 // 6.4 MB
    _Float16* t_h = (_Float16*)alloc((size_t)NN * D * 2);        // 12.8 MB
    // scratch region: pbuf 17.2MB + qloc 7.0MB = 24.2MB; dead after finalize,
    // then t2p (12.8MB fp16, panel-major) aliases its start.
    char* scratch = (char*)alloc((size_t)NBD * KB * CAPD * 4 + (size_t)NBS * KB * CAPS);
    (void)ws_size;
    int* pbuf = (int*)scratch;
    unsigned char* qloc = (unsigned char*)(pbuf + (size_t)NBD * KB * CAPD);
    _Float16* t2p = (_Float16*)scratch;

    partition_tf1_kernel<<<KB + TFB, PTB, 0, stream>>>(src, dst, cntD, cntS,
                                                       pbuf, qloc, x, W1, t_h);
    scan1_kernel<<<NBD, 256, 0, stream>>>(cntD, btot);
    finalize_kernel<<<NBD + NBS, PTB, 0, stream>>>(pbuf, qloc, cntD, cntS, btot,
                                                   row_ptr, nsrc, ndst, esrc);

    agg_tf_kernel<<<AGTB, 256, 0, stream>>>(t_h, row_ptr, esrc, nsrc, ndst, b1, W2, t2p);
    // 8 panels x 6250 node-blocks (16 nodes/block); panel = bid&7 -> per-XCD L2 pinning
    agg2_panel_kernel<<<8 * 6250, 256, 0, stream>>>(t2p, row_ptr, esrc, ndst, b2, out);
}

// Round 14
// 218.279 us; speedup vs baseline: 1.6522x; 1.2046x over previous
//
#include <hip/hip_runtime.h>
#include <math.h>

#define NN 100000
#define NE 1600000
#define D 64
#define NQ (NE / 4)

#define NBD 196                     // dst buckets, width 512 (dst>>9)
#define NBS 391                     // src buckets, width 256 (src>>8)

#define KB 500                      // partition blocks (both sides per block)
#define QPB (NQ / KB)               // 800 int4 quads per block (exact)
#define CAPD 44                     // dst cell cap, ints  (lambda 16.3, +6.9s, 1e-6 agg)
#define CAPS 36                     // src cell cap, bytes (lambda 8.2,  +9.4s, 2e-6 agg)
#define NWD (NBD * CAPD)            // 8624 staged dst words per block
#define NWS (NBS * CAPS / 4)        // 3519 staged src words per block (36 = 4*9)
#define ESCAP 8704                  // esrc LDS stage cap (bucket lambda 8192, +5.7 sigma)
#define PTB 512
#define TFB 782                     // tf1 blocks: 128 nodes each (782*128=100096)
#define AGTB 1563                   // fused agg+tf blocks: 64 nodes each (1563*64=100032)

typedef _Float16 h4v __attribute__((ext_vector_type(4)));
typedef _Float16 h8v __attribute__((ext_vector_type(8)));

// ============ tiled transform core (r7/r8-proven): 64-node tile, 4 waves ==============
__device__ __forceinline__ void tile_tf(
    const float* __restrict__ in, const float* __restrict__ W,
    const float* __restrict__ scale, _Float16* __restrict__ out,
    float* xT, int tileBase, int lt /*0..255*/)
{
    {
        int c4 = (lt & 15) << 2;
        int r0 = lt >> 4;
#pragma unroll
        for (int p = 0; p < 4; ++p) {
            int r = r0 + (p << 4);
            int node = tileBase + r;
            int nl = node < NN ? node : NN - 1;
            float4 v = *(const float4*)(in + (size_t)nl * D + c4);
            xT[(c4 + 0) * 64 + (r ^ c4)] = v.x;
            xT[(c4 + 1) * 64 + (r ^ c4)] = v.y;
            xT[(c4 + 2) * 64 + (r ^ c4)] = v.z;
            xT[(c4 + 3) * 64 + (r ^ c4)] = v.w;
        }
    }
    __syncthreads();
    int lane = lt & 63;
    int w = lt >> 6;
    int m0 = (lane >> 2) << 2;
    int nc = (w << 4) + ((lane & 3) << 2);
    float4 a0 = {0,0,0,0}, a1 = {0,0,0,0}, a2 = {0,0,0,0}, a3 = {0,0,0,0};
#pragma unroll 8
    for (int k = 0; k < 64; ++k) {
        int P = k & 60;
        float4 xa = *(const float4*)(xT + k * 64 + (m0 ^ P));
        float4 wv = *(const float4*)(W + k * D + nc);
        a0.x += xa.x * wv.x; a0.y += xa.x * wv.y; a0.z += xa.x * wv.z; a0.w += xa.x * wv.w;
        a1.x += xa.y * wv.x; a1.y += xa.y * wv.y; a1.z += xa.y * wv.z; a1.w += xa.y * wv.w;
        a2.x += xa.z * wv.x; a2.y += xa.z * wv.y; a2.z += xa.z * wv.z; a2.w += xa.z * wv.w;
        a3.x += xa.w * wv.x; a3.y += xa.w * wv.y; a3.z += xa.w * wv.z; a3.w += xa.w * wv.w;
    }
    float4 acc[4] = {a0, a1, a2, a3};
#pragma unroll
    for (int j = 0; j < 4; ++j) {
        int node = tileBase + m0 + j;
        if (node < NN) {
            float sc = scale ? scale[node] : 1.0f;
            h4v o;
            o[0] = (_Float16)(acc[j].x * sc); o[1] = (_Float16)(acc[j].y * sc);
            o[2] = (_Float16)(acc[j].z * sc); o[3] = (_Float16)(acc[j].w * sc);
            *(h4v*)(out + (size_t)node * D + nc) = o;
        }
    }
}

// ---------------- K1 (fused): blocks [0,KB) partition | [KB,KB+TFB) transform1 --------
__global__ __launch_bounds__(PTB) void partition_tf1_kernel(
    const int* __restrict__ src, const int* __restrict__ dst,
    int* __restrict__ cntD, int* __restrict__ cntS,
    int* __restrict__ pbuf, unsigned char* __restrict__ qloc,
    const float* __restrict__ x, const float* __restrict__ W1,
    _Float16* __restrict__ t_h)
{
    __shared__ __align__(16) char smem[50944];
    int t = threadIdx.x, b = blockIdx.x;
    if (b >= KB) {
        int half = t >> 8;
        int lt = t & 255;
        tile_tf(x, W1, (const float*)0, t_h,
                (float*)smem + half * (64 * 64), (b - KB) * 128 + half * 64, lt);
        return;
    }
    int* stageD = (int*)smem;                       // 8624 ints
    int* hD = (int*)(smem + 34496);                 // 196 cursors
    int* hS = (int*)(smem + 35280);                 // 391 cursors
    unsigned char* stageS = (unsigned char*)(smem + 36844);   // 14076 bytes
    for (int i = t; i < NBD; i += PTB) hD[i] = i * CAPD;
    for (int i = t; i < NBS; i += PTB) hS[i] = i * CAPS;
    __syncthreads();
    const int4* s4 = (const int4*)src + (size_t)b * QPB;
    const int4* d4 = (const int4*)dst + (size_t)b * QPB;
    for (int i = t; i < QPB; i += PTB) {
        int4 a = s4[i], d = d4[i];
        int p;
        p = atomicAdd(&hD[d.x >> 9], 1); stageD[p] = ((d.x & 511) << 17) | a.x;
        p = atomicAdd(&hD[d.y >> 9], 1); stageD[p] = ((d.y & 511) << 17) | a.y;
        p = atomicAdd(&hD[d.z >> 9], 1); stageD[p] = ((d.z & 511) << 17) | a.z;
        p = atomicAdd(&hD[d.w >> 9], 1); stageD[p] = ((d.w & 511) << 17) | a.w;
        p = atomicAdd(&hS[a.x >> 8], 1); stageS[p] = (unsigned char)(a.x & 255);
        p = atomicAdd(&hS[a.y >> 8], 1); stageS[p] = (unsigned char)(a.y & 255);
        p = atomicAdd(&hS[a.z >> 8], 1); stageS[p] = (unsigned char)(a.z & 255);
        p = atomicAdd(&hS[a.w >> 8], 1); stageS[p] = (unsigned char)(a.w & 255);
    }
    __syncthreads();
    for (int i = t; i < NWD; i += PTB) {
        int bkt = i / CAPD, slot = i - bkt * CAPD;
        pbuf[((size_t)bkt * KB + b) * CAPD + slot] = stageD[i];
    }
    const int* stageS_w = (const int*)(smem + 36844);
    int* qloc_w = (int*)qloc;
    for (int i = t; i < NWS; i += PTB) {
        int bkt = i / 9, sw = i - bkt * 9;
        qloc_w[((size_t)bkt * KB + b) * 9 + sw] = stageS_w[i];
    }
    for (int i = t; i < NBD; i += PTB) cntD[i * KB + b] = hD[i] - i * CAPD;
    for (int i = t; i < NBS; i += PTB) cntS[i * KB + b] = hS[i] - i * CAPS;
}

// ---------------- K2: per-bucket totals ----------------
__global__ __launch_bounds__(256) void scan1_kernel(const int* __restrict__ cntD,
                                                    int* __restrict__ btot) {
    int B = blockIdx.x, t = threadIdx.x;
    __shared__ int ps[4];
    int s = 0;
    for (int j = t; j < KB; j += 256) s += cntD[B * KB + j];
    for (int o = 32; o > 0; o >>= 1) s += __shfl_xor(s, o, 64);
    if ((t & 63) == 0) ps[t >> 6] = s;
    __syncthreads();
    if (t == 0) btot[B] = ps[0] + ps[1] + ps[2] + ps[3];
}

// ---------------- K3: finalize — in-block prefix, LDS-staged esrc (r10-proven) --------
__global__ __launch_bounds__(PTB) void finalize_kernel(
    const int* __restrict__ pbuf, const unsigned char* __restrict__ qloc,
    const int* __restrict__ cntD, const int* __restrict__ cntS,
    const int* __restrict__ btot,
    int* __restrict__ row_ptr, float* __restrict__ nsrc,
    float* __restrict__ ndst, int* __restrict__ esrc)
{
    int B = blockIdx.x, t = threadIdx.x;
    int lane = t & 63, w = t >> 6;
    if (B >= NBD) {
        int q = B - NBD;
        __shared__ int h[256];
        __shared__ int cs[KB];
        if (t < 256) h[t] = 0;
        if (t < KB) cs[t] = cntS[q * KB + t];
        __syncthreads();
        for (int r0 = 0; r0 < KB; r0 += 64) {
            int r = r0 + (w << 3) + (lane >> 3);
            if (r < KB) {
                int c = cs[r];
                const unsigned char* run = qloc + ((size_t)q * KB + r) * CAPS;
                for (int k = lane & 7; k < c; k += 8) atomicAdd(&h[run[k]], 1);
            }
        }
        __syncthreads();
        if (t < 256) {
            int n = (q << 8) + t;
            if (n < NN) nsrc[n] = 1.0f / sqrtf(fmaxf((float)h[t], 1.0f));
        }
        return;
    }
    __shared__ int fh[512], fcur[512];
    __shared__ int cl[KB];
    __shared__ int stage[ESCAP];
    __shared__ int sbeg;
    if (t < KB) cl[t] = cntD[B * KB + t];
    for (int i = t; i < 512; i += PTB) fh[i] = 0;
    if (w == 0) {
        int s = 0;
        for (int j = lane; j < B; j += 64) s += btot[j];
        for (int o = 32; o > 0; o >>= 1) s += __shfl_xor(s, o, 64);
        if (lane == 0) sbeg = s;
    }
    if (B == 0 && t == 128) row_ptr[NN] = NE;
    __syncthreads();
    int beg = sbeg;
    for (int r0 = 0; r0 < KB; r0 += 32) {
        int r = r0 + (w << 2) + (lane >> 4);
        if (r < KB) {
            int c = cl[r];
            const int* run = pbuf + ((size_t)B * KB + r) * CAPD;
            for (int k = lane & 15; k < c; k += 16) atomicAdd(&fh[run[k] >> 17], 1);
        }
    }
    __syncthreads();
    if (w == 0) {
        int v[8];
        int s = 0;
#pragma unroll
        for (int j = 0; j < 8; ++j) { v[j] = fh[lane * 8 + j]; s += v[j]; }
        int incl = s;
        for (int o = 1; o < 64; o <<= 1) {
            int u = __shfl_up(incl, o, 64);
            if (lane >= o) incl += u;
        }
        int run = incl - s;
#pragma unroll
        for (int j = 0; j < 8; ++j) {
            int bin = lane * 8 + j;
            fcur[bin] = run;
            int n = (B << 9) + bin;
            if (n < NN) {
                row_ptr[n] = beg + run;
                ndst[n] = 1.0f / sqrtf(fmaxf((float)v[j], 1.0f));
            }
            run += v[j];
        }
    }
    __syncthreads();
    for (int r0 = 0; r0 < KB; r0 += 32) {
        int r = r0 + (w << 2) + (lane >> 4);
        if (r < KB) {
            int c = cl[r];
            const int* run = pbuf + ((size_t)B * KB + r) * CAPD;
            for (int k = lane & 15; k < c; k += 16) {
                int v = run[k];
                int p = atomicAdd(&fcur[v >> 17], 1);
                stage[p] = v & 0x1FFFF;
            }
        }
    }
    __syncthreads();
    int cnt = btot[B];
    for (int i = t; i < cnt; i += PTB) esrc[beg + i] = stage[i];
}

// ---------------- K4 (fused): aggregate-1 + transform-2 (r11-proven) ----------------
__global__ __launch_bounds__(256) void agg_tf_kernel(
    const _Float16* __restrict__ t, const int* __restrict__ row_ptr,
    const int* __restrict__ esrc, const float* __restrict__ nsrc,
    const float* __restrict__ ndst, const float* __restrict__ bias,
    const float* __restrict__ W, _Float16* __restrict__ out)
{
    __shared__ float xT[64 * 64];       // 16 KB
    int tid = threadIdx.x;
    int lane = tid & 63, wv = tid >> 6;     // 4 waves
    int tileBase = blockIdx.x * 64;
    int quad = lane >> 4;
    int l4 = lane & 15;
    int g = l4 >> 3, c = l4 & 7;
    float4 blo = *(const float4*)(bias + (c << 3));
    float4 bhi = *(const float4*)(bias + (c << 3) + 4);
#pragma unroll 1
    for (int pass = 0; pass < 4; ++pass) {
        int m = (wv << 4) + (pass << 2) + quad;     // node-in-tile 0..63
        int node = tileBase + m;
        float a0[8] = {0,0,0,0,0,0,0,0};
        float a1[8] = {0,0,0,0,0,0,0,0};
        float h[8];
        if (node < NN) {
            int beg = row_ptr[node], end = row_ptr[node + 1];
            int i = beg;
            for (; i + 4 <= end; i += 4) {
                int s0 = esrc[i + g];
                int s1 = esrc[i + 2 + g];
                float ns0 = nsrc[s0];
                float ns1 = nsrc[s1];
                h8v v0 = *(const h8v*)(t + (size_t)s0 * D + (c << 3));
                h8v v1 = *(const h8v*)(t + (size_t)s1 * D + (c << 3));
#pragma unroll
                for (int j = 0; j < 8; ++j) {
                    a0[j] += (float)v0[j] * ns0;
                    a1[j] += (float)v1[j] * ns1;
                }
            }
            for (; i < end; i += 2) {
                int e = i + g;
                if (e < end) {
                    int s = esrc[e];
                    float ns = nsrc[s];
                    h8v v = *(const h8v*)(t + (size_t)s * D + (c << 3));
#pragma unroll
                    for (int j = 0; j < 8; ++j) a0[j] += (float)v[j] * ns;
                }
            }
#pragma unroll
            for (int j = 0; j < 8; ++j) a0[j] += a1[j];
#pragma unroll
            for (int j = 0; j < 8; ++j) a0[j] += __shfl_xor(a0[j], 8, 64);
            float nd = ndst[node];
            h[0] = fmaxf(a0[0] * nd + blo.x, 0.f); h[1] = fmaxf(a0[1] * nd + blo.y, 0.f);
            h[2] = fmaxf(a0[2] * nd + blo.z, 0.f); h[3] = fmaxf(a0[3] * nd + blo.w, 0.f);
            h[4] = fmaxf(a0[4] * nd + bhi.x, 0.f); h[5] = fmaxf(a0[5] * nd + bhi.y, 0.f);
            h[6] = fmaxf(a0[6] * nd + bhi.z, 0.f); h[7] = fmaxf(a0[7] * nd + bhi.w, 0.f);
        } else {
#pragma unroll
            for (int j = 0; j < 8; ++j) h[j] = 0.f;
        }
#pragma unroll
        for (int j = 0; j < 4; ++j) {
            int k = (c << 3) + (g << 2) + j;
            xT[k * 64 + (m ^ (k & 60))] = h[(g << 2) + j];
        }
    }
    __syncthreads();
    int m0 = (lane >> 2) << 2;
    int nc = (wv << 4) + ((lane & 3) << 2);
    float4 b0 = {0,0,0,0}, b1_ = {0,0,0,0}, b2_ = {0,0,0,0}, b3 = {0,0,0,0};
#pragma unroll 8
    for (int k = 0; k < 64; ++k) {
        int P = k & 60;
        float4 xa = *(const float4*)(xT + k * 64 + (m0 ^ P));
        float4 wv4 = *(const float4*)(W + k * D + nc);
        b0.x += xa.x * wv4.x; b0.y += xa.x * wv4.y; b0.z += xa.x * wv4.z; b0.w += xa.x * wv4.w;
        b1_.x += xa.y * wv4.x; b1_.y += xa.y * wv4.y; b1_.z += xa.y * wv4.z; b1_.w += xa.y * wv4.w;
        b2_.x += xa.z * wv4.x; b2_.y += xa.z * wv4.y; b2_.z += xa.z * wv4.z; b2_.w += xa.z * wv4.w;
        b3.x += xa.w * wv4.x; b3.y += xa.w * wv4.y; b3.z += xa.w * wv4.z; b3.w += xa.w * wv4.w;
    }
    float4 acc[4] = {b0, b1_, b2_, b3};
#pragma unroll
    for (int j = 0; j < 4; ++j) {
        int node = tileBase + m0 + j;
        if (node < NN) {
            float sc = nsrc[node];
            h4v o;
            o[0] = (_Float16)(acc[j].x * sc); o[1] = (_Float16)(acc[j].y * sc);
            o[2] = (_Float16)(acc[j].z * sc); o[3] = (_Float16)(acc[j].w * sc);
            *(h4v*)(out + (size_t)node * D + nc) = o;
        }
    }
}

// ---------------- K5: aggregation layer 2 (r10-proven; no relu, no nsrc) --------------
template<int RELU, int USE_NSRC>
__global__ __launch_bounds__(256) void aggregate_kernel(const _Float16* __restrict__ t,
                                                        const int* __restrict__ row_ptr,
                                                        const int* __restrict__ esrc,
                                                        const float* __restrict__ nsrc,
                                                        const float* __restrict__ ndst,
                                                        const float* __restrict__ bias,
                                                        float* __restrict__ out) {
    int wid = (blockIdx.x * 256 + threadIdx.x) >> 6;
    int lane = threadIdx.x & 63;
    int quad = lane >> 4;
    int l4 = lane & 15;
    int g = l4 >> 3, c = l4 & 7;
    int node = wid * 4 + quad;
    if (node >= NN) return;
    int beg = row_ptr[node], end = row_ptr[node + 1];
    float a0[8] = {0,0,0,0,0,0,0,0};
    float a1[8] = {0,0,0,0,0,0,0,0};
    int i = beg;
    for (; i + 4 <= end; i += 4) {
        int s0 = esrc[i + g];
        int s1 = esrc[i + 2 + g];
        float ns0 = USE_NSRC ? nsrc[s0] : 1.0f;
        float ns1 = USE_NSRC ? nsrc[s1] : 1.0f;
        h8v v0 = *(const h8v*)(t + (size_t)s0 * D + (c << 3));
        h8v v1 = *(const h8v*)(t + (size_t)s1 * D + (c << 3));
#pragma unroll
        for (int j = 0; j < 8; ++j) {
            if (USE_NSRC) { a0[j] += (float)v0[j] * ns0; a1[j] += (float)v1[j] * ns1; }
            else          { a0[j] += (float)v0[j];       a1[j] += (float)v1[j]; }
        }
    }
    for (; i < end; i += 2) {
        int e = i + g;
        if (e < end) {
            int s = esrc[e];
            float ns = USE_NSRC ? nsrc[s] : 1.0f;
            h8v v = *(const h8v*)(t + (size_t)s * D + (c << 3));
#pragma unroll
            for (int j = 0; j < 8; ++j) {
                if (USE_NSRC) a0[j] += (float)v[j] * ns;
                else          a0[j] += (float)v[j];
            }
        }
    }
#pragma unroll
    for (int j = 0; j < 8; ++j) a0[j] += a1[j];
#pragma unroll
    for (int j = 0; j < 8; ++j) {
        a0[j] += __shfl_xor(a0[j], 8, 64);
    }
    float nd = ndst[node];
    float4 blo = *(const float4*)(bias + (c << 3));
    float4 bhi = *(const float4*)(bias + (c << 3) + 4);
    float h[8];
    h[0] = a0[0] * nd + blo.x; h[1] = a0[1] * nd + blo.y;
    h[2] = a0[2] * nd + blo.z; h[3] = a0[3] * nd + blo.w;
    h[4] = a0[4] * nd + bhi.x; h[5] = a0[5] * nd + bhi.y;
    h[6] = a0[6] * nd + bhi.z; h[7] = a0[7] * nd + bhi.w;
    if (RELU) {
#pragma unroll
        for (int j = 0; j < 8; ++j) h[j] = fmaxf(h[j], 0.f);
    }
    if (g == 0) {
        float4 o0 = {h[0], h[1], h[2], h[3]};
        float4 o1 = {h[4], h[5], h[6], h[7]};
        *(float4*)(out + (size_t)node * D + (c << 3)) = o0;
        *(float4*)(out + (size_t)node * D + (c << 3) + 4) = o1;
    }
}

// ---------------- launcher ----------------
extern "C" void kernel_launch(void* const* d_in, const int* in_sizes, int n_in,
                              void* d_out, int out_size, void* d_ws, size_t ws_size,
                              hipStream_t stream) {
    const float* x  = (const float*)d_in[0];
    const int* src  = (const int*)d_in[1];
    const int* dst  = (const int*)d_in[2];
    const float* W1 = (const float*)d_in[3];
    const float* b1 = (const float*)d_in[4];
    const float* W2 = (const float*)d_in[5];
    const float* b2 = (const float*)d_in[6];
    float* out = (float*)d_out;

    size_t off = 0;
    auto alloc = [&](size_t bytes) -> void* {
        void* p = (char*)d_ws + off;
        off += (bytes + 255) & ~(size_t)255;
        return p;
    };
    int* row_ptr  = (int*)alloc((size_t)(NN + 1) * 4);
    float* nsrc   = (float*)alloc((size_t)NN * 4);
    float* ndst   = (float*)alloc((size_t)NN * 4);
    int* btot     = (int*)alloc((size_t)256 * 4);
    int* cntD     = (int*)alloc((size_t)NBD * KB * 4);           // 392 KB
    int* cntS     = (int*)alloc((size_t)NBS * KB * 4);           // 782 KB
    int* esrc     = (int*)alloc((size_t)NE * 4);                 // 6.4 MB
    _Float16* t_h = (_Float16*)alloc((size_t)NN * D * 2);        // 12.8 MB
    // scratch region: pbuf 17.2MB + qloc 7.0MB = 24.2MB; dead after finalize,
    // then t2 (12.8MB fp16) aliases its start.
    char* scratch = (char*)alloc((size_t)NBD * KB * CAPD * 4 + (size_t)NBS * KB * CAPS);
    (void)ws_size;
    int* pbuf = (int*)scratch;
    unsigned char* qloc = (unsigned char*)(pbuf + (size_t)NBD * KB * CAPD);
    _Float16* t2 = (_Float16*)scratch;

    partition_tf1_kernel<<<KB + TFB, PTB, 0, stream>>>(src, dst, cntD, cntS,
                                                       pbuf, qloc, x, W1, t_h);
    scan1_kernel<<<NBD, 256, 0, stream>>>(cntD, btot);
    finalize_kernel<<<NBD + NBS, PTB, 0, stream>>>(pbuf, qloc, cntD, cntS, btot,
                                                   row_ptr, nsrc, ndst, esrc);

    agg_tf_kernel<<<AGTB, 256, 0, stream>>>(t_h, row_ptr, esrc, nsrc, ndst, b1, W2, t2);
    aggregate_kernel<0, 0><<<6250, 256, 0, stream>>>(t2, row_ptr, esrc, nsrc, ndst, b2, out);
}